// Round 1
// baseline (85.512 us; speedup 1.0000x reference)
//
#include <hip/hip_runtime.h>
#include <stdint.h>

#define UNITS  512
#define IN_DIM 1024
#define KCONN  32
#define BATCH  16384
#define BTILE  16

// ---------------- Kernel 1: top-32 per unit ----------------
// pert[u,i] = D[u,i] + GN[0,u,i]; select 32 largest (tie -> lower index, like
// jax.lax.top_k). Only the index SET matters downstream (one-hots are summed).
// Output transposed+packed: pkT[k*UNITS + u] = { idx*4 (byte offset), bits(W[u,idx]) }

__device__ __forceinline__ uint32_t ordkey(float f) {
    uint32_t b = __float_as_uint(f);
    uint32_t mask = (b & 0x80000000u) ? 0xFFFFFFFFu : 0x80000000u;
    return b ^ mask;  // monotone: larger float -> larger uint
}

__global__ __launch_bounds__(64) void topk_kernel(const float* __restrict__ D,
                                                  const float* __restrict__ GN,
                                                  const float* __restrict__ W,
                                                  uint2* __restrict__ pkT) {
    const int u = blockIdx.x;
    const int l = threadIdx.x;

    // key = ord(value)<<32 | (0xFFFFFFFF - i): max key = max value, tie -> smaller i
    unsigned long long keys[16];
#pragma unroll
    for (int j = 0; j < 16; ++j) {
        int i = l + 64 * j;                          // coalesced
        float v = D[u * IN_DIM + i] + GN[u * IN_DIM + i];
        keys[j] = ((unsigned long long)ordkey(v) << 32) |
                  (uint32_t)(0xFFFFFFFFu - (uint32_t)i);
    }
    unsigned long long best = keys[0];
#pragma unroll
    for (int j = 1; j < 16; ++j) best = keys[j] > best ? keys[j] : best;

    __shared__ int idxbuf[KCONN];

    for (int t = 0; t < KCONN; ++t) {
        unsigned long long g = best;
#pragma unroll
        for (int s = 1; s < 64; s <<= 1) {
            unsigned long long o = __shfl_xor(g, s, 64);
            g = o > g ? o : g;
        }
        if (best == g) {                // unique owner (keys unique via index bits)
            int i = (int)(0xFFFFFFFFu - (uint32_t)g);
            idxbuf[t] = i;
            int slot = i >> 6;
#pragma unroll
            for (int j = 0; j < 16; ++j)            // static indexing (no scratch)
                if (j == slot) keys[j] = 0;
            best = keys[0];
#pragma unroll
            for (int j = 1; j < 16; ++j) best = keys[j] > best ? keys[j] : best;
        }
    }
    __syncthreads();
    if (l < KCONN) {
        int i = idxbuf[l];
        float w = W[u * IN_DIM + i];
        pkT[l * UNITS + u] = make_uint2((uint32_t)(i * 4), __float_as_uint(w));
    }
}

// ---------------- Kernel 2: sparse gather-GEMM ----------------
// y[b,u] = bias[u] + sum_k W[u,idx] * x[b,idx]
// Block: 16 batch rows staged in LDS (64KB f32, exact). 8 waves; lane = unit
// (u = wave*64 + lane). acc[16] = one f32 per batch row, statically indexed.
// Per k: 1 coalesced pkT load/wave, then 16x {ds_read_b32 offset:4096*b, fmac}.
// Stores: consecutive lanes -> consecutive units -> 256B coalesced.

__global__ __launch_bounds__(512) void spmm_kernel(const float* __restrict__ x,
                                                   const float* __restrict__ bias,
                                                   const uint2* __restrict__ pkT,
                                                   float* __restrict__ y) {
    __shared__ float xs[BTILE * IN_DIM];   // 64 KB -> 2 blocks/CU co-resident

    const int b0 = blockIdx.x * BTILE;

    // stage 16 rows of x, float4-vectorized, fully coalesced
    const float4* g4 = (const float4*)(x + (size_t)b0 * IN_DIM);
    float4* s4 = (float4*)xs;
#pragma unroll
    for (int r = 0; r < 8; ++r) {
        int f = threadIdx.x + 512 * r;     // 4096 float4 total
        s4[f] = g4[f];
    }
    __syncthreads();

    const int w = threadIdx.x >> 6;
    const int l = threadIdx.x & 63;
    const int u = w * 64 + l;

    float acc[BTILE];
    const float bv = bias[u];
#pragma unroll
    for (int b = 0; b < BTILE; ++b) acc[b] = bv;

#pragma unroll 4
    for (int k = 0; k < KCONN; ++k) {
        uint2 p = pkT[(k << 9) + u];                 // coalesced 512B per wave
        float wv = __uint_as_float(p.y);
        const float* xp = (const float*)((const char*)xs + p.x);
#pragma unroll
        for (int b = 0; b < BTILE; ++b) {
            acc[b] = fmaf(xp[b * IN_DIM], wv, acc[b]);   // ds_read_b32 offset:4096*b
        }
    }

    float* yp = y + (size_t)b0 * UNITS + u;
#pragma unroll
    for (int b = 0; b < BTILE; ++b) yp[b * UNITS] = acc[b];   // 256B coalesced
}

extern "C" void kernel_launch(void* const* d_in, const int* in_sizes, int n_in,
                              void* d_out, int out_size, void* d_ws, size_t ws_size,
                              hipStream_t stream) {
    const float* x  = (const float*)d_in[0];   // [16384,1024]
    const float* W  = (const float*)d_in[1];   // [512,1024]
    const float* bv = (const float*)d_in[2];   // [512]
    const float* D  = (const float*)d_in[3];   // [512,1024]
    const float* GN = (const float*)d_in[4];   // [1,512,1024]
    float* y = (float*)d_out;                  // [16384,512]

    uint2* pkT = (uint2*)d_ws;                 // 32*512*8B = 128KB scratch

    topk_kernel<<<UNITS, 64, 0, stream>>>(D, GN, W, pkT);
    spmm_kernel<<<BATCH / BTILE, 512, 0, stream>>>(x, bv, pkT, y);
}

// Round 2
// 60.762 us; speedup vs baseline: 1.4073x; 1.4073x over previous
//
#include <hip/hip_runtime.h>
#include <stdint.h>

#define UNITS  512
#define IN_DIM 1024
#define KCONN  32
#define BATCH  16384
#define BT     32   // batch rows per spmm block

// ---------------- Kernel 1: top-32 per unit ----------------
// pert[u,i] = D[u,i] + GN[0,u,i]; select the 32 largest (tie -> lower index,
// matching jax.lax.top_k). Only the index SET matters (summed one-hots), so
// slot order is irrelevant. Output transposed+packed:
//   pkT[k*UNITS + u] = { i*64 (xs_T row byte offset), bits(W[u,i]) }

__device__ __forceinline__ uint32_t ordkey(float f) {
    uint32_t b = __float_as_uint(f);
    uint32_t mask = (b & 0x80000000u) ? 0xFFFFFFFFu : 0x80000000u;
    return b ^ mask;  // monotone: larger float -> larger uint
}

__global__ __launch_bounds__(64) void topk_kernel(const float* __restrict__ D,
                                                  const float* __restrict__ GN,
                                                  const float* __restrict__ W,
                                                  uint2* __restrict__ pkT) {
    const int u = blockIdx.x;
    const int l = threadIdx.x;

    // key = ord(value)<<32 | (0xFFFFFFFF - i): max key = max value, tie -> smaller i
    unsigned long long keys[16];
#pragma unroll
    for (int j = 0; j < 16; ++j) {
        int i = l + 64 * j;                          // coalesced
        float v = D[u * IN_DIM + i] + GN[u * IN_DIM + i];
        keys[j] = ((unsigned long long)ordkey(v) << 32) |
                  (uint32_t)(0xFFFFFFFFu - (uint32_t)i);
    }
    unsigned long long best = keys[0];
#pragma unroll
    for (int j = 1; j < 16; ++j) best = keys[j] > best ? keys[j] : best;

    __shared__ int idxbuf[KCONN];

    for (int t = 0; t < KCONN; ++t) {
        unsigned long long g = best;
#pragma unroll
        for (int s = 1; s < 64; s <<= 1) {
            unsigned long long o = __shfl_xor(g, s, 64);
            g = o > g ? o : g;
        }
        if (best == g) {                // unique owner (keys unique via index bits)
            int i = (int)(0xFFFFFFFFu - (uint32_t)g);
            idxbuf[t] = i;
            int slot = i >> 6;
#pragma unroll
            for (int j = 0; j < 16; ++j)            // static indexing (no scratch)
                if (j == slot) keys[j] = 0;
            best = keys[0];
#pragma unroll
            for (int j = 1; j < 16; ++j) best = keys[j] > best ? keys[j] : best;
        }
    }
    __syncthreads();
    if (l < KCONN) {
        int i = idxbuf[l];
        float w = W[u * IN_DIM + i];
        pkT[l * UNITS + u] = make_uint2((uint32_t)(i << 6), __float_as_uint(w));
    }
}

// ---------------- Kernel 2: sparse gather-GEMM ----------------
// y[b,u] = bias[u] + sum_k W[u,idx] * x[b,idx]
// LDS: xs_T[i][b] bf16, 32 batch/row = 64B rows, 64 KB -> 2 blocks/CU.
// XOR swizzle within each row (16B granules): phys = i*64 + (off ^ (((i>>1)&3)<<4))
//   -> staging ds_write_b64 conflict-free; gather ds_read_b128 reads a full row
//      per 4-lane group (bank-balanced up to even/odd-row skew ~1.2x).
// Compute: lane l: unit group g=l>>2 (16 units/wave), batch quarter s=l&3
//   (8 batches/lane). Per k: 1 ds_read_b128 = 8 bf16 batches -> 8 fmac (f32 acc).
//   4 unit passes x 32 k. 16x fewer LDS instrs, 2x fewer LDS bytes than v1.

__device__ __forceinline__ uint32_t f2bf_rne(float f) {
    uint32_t u = __float_as_uint(f);
    return (u + 0x7fffu + ((u >> 16) & 1u)) >> 16;   // round-to-nearest-even
}
__device__ __forceinline__ float bf_lo(uint32_t v) { return __uint_as_float(v << 16); }
__device__ __forceinline__ float bf_hi(uint32_t v) { return __uint_as_float(v & 0xffff0000u); }

__global__ __launch_bounds__(512, 4) void spmm_kernel(const float* __restrict__ x,
                                                      const float* __restrict__ bias,
                                                      const uint2* __restrict__ pkT,
                                                      float* __restrict__ y) {
    __shared__ uint4 xs4[4096];                 // 64 KB
    char* xsb = (char*)xs4;

    const int tid = threadIdx.x;
    const int w = tid >> 6;                     // wave 0..7
    const int l = tid & 63;
    const int r = l & 3;                        // quad lane
    const int q = l >> 2;                       // quad id 0..15
    const int b0 = blockIdx.x * BT;

    // ---- stage: x[b0..b0+31][0..1023] f32 -> bf16 xs_T[i][b], transposed ----
    // wave w owns batch rows 4w..4w+3 (lane r = row). quad q covers cols q*4+64j.
    const float* xrow = x + (size_t)(b0 + 4 * w + r) * IN_DIM;
    const int r1 = r & 1, r2 = r & 2;
#pragma unroll
    for (int j = 0; j < 16; ++j) {
        const int c = (q << 2) + (j << 6);
        float4 v = *(const float4*)(xrow + c);
        float f0 = v.x, f1 = v.y, f2 = v.z, f3 = v.w;
        // pre-rotate left by r: g[m] = f[(m+r)&3]
        float t0 = r1 ? f1 : f0, t1 = r1 ? f2 : f1, t2 = r1 ? f3 : f2, t3 = r1 ? f0 : f3;
        float g0 = r2 ? t2 : t0, g1 = r2 ? t3 : t1, g2 = r2 ? t0 : t2, g3 = r2 ? t1 : t3;
        // column shuffle within quad: tmp[m] = g[m] of quad-lane (r-m)&3
        const int qb = l & ~3;
        float m0 = __shfl(g0, qb | (r & 3), 64);
        float m1 = __shfl(g1, qb | ((r - 1) & 3), 64);
        float m2 = __shfl(g2, qb | ((r - 2) & 3), 64);
        float m3 = __shfl(g3, qb | ((r - 3) & 3), 64);
        // out[m] = tmp[(r-m)&3]: reverse, then rotate right by r
        float e0 = m0, e1 = m3, e2 = m2, e3 = m1;
        float s0 = r1 ? e3 : e0, s1 = r1 ? e0 : e1, s2 = r1 ? e1 : e2, s3 = r1 ? e2 : e3;
        float o0 = r2 ? s2 : s0, o1 = r2 ? s3 : s1, o2 = r2 ? s0 : s2, o3 = r2 ? s1 : s3;
        // o0..o3 = x[b0+4w+0..3][c+r] -> pack 4 bf16, write 8B at batch offset 8w
        const int i = c + r;
        uint32_t lo = f2bf_rne(o0) | (f2bf_rne(o1) << 16);
        uint32_t hi = f2bf_rne(o2) | (f2bf_rne(o3) << 16);
        uint32_t phys = (uint32_t)(i << 6) + (((uint32_t)(w << 3)) ^ ((uint32_t)(i & 6) << 3));
        *(uint2*)(xsb + phys) = make_uint2(lo, hi);
    }
    __syncthreads();

    // ---- gather-GEMM ----
    const uint32_t sw = (uint32_t)(r << 4);     // logical 16B chunk = batches 8r..8r+7
#pragma unroll 1
    for (int p = 0; p < 4; ++p) {
        const int u = (p << 7) + (w << 4) + q;
        const float bv = bias[u];
        float a0 = bv, a1 = bv, a2 = bv, a3 = bv, a4 = bv, a5 = bv, a6 = bv, a7 = bv;
#pragma unroll 8
        for (int k = 0; k < KCONN; ++k) {
            uint2 pk = pkT[(k << 9) + u];       // .x = i*64, .y = bits(W)
            uint32_t phys = pk.x + (sw ^ ((pk.x >> 3) & 0x30u));
            uint4 xv = *(const uint4*)(xsb + phys);   // ds_read_b128: 8 bf16 batches
            float wv = __uint_as_float(pk.y);
            a0 = fmaf(bf_lo(xv.x), wv, a0);
            a1 = fmaf(bf_hi(xv.x), wv, a1);
            a2 = fmaf(bf_lo(xv.y), wv, a2);
            a3 = fmaf(bf_hi(xv.y), wv, a3);
            a4 = fmaf(bf_lo(xv.z), wv, a4);
            a5 = fmaf(bf_hi(xv.z), wv, a5);
            a6 = fmaf(bf_lo(xv.w), wv, a6);
            a7 = fmaf(bf_hi(xv.w), wv, a7);
        }
        float* yp = y + (size_t)(b0 + (r << 3)) * UNITS + u;
        yp[0 * UNITS] = a0; yp[1 * UNITS] = a1; yp[2 * UNITS] = a2; yp[3 * UNITS] = a3;
        yp[4 * UNITS] = a4; yp[5 * UNITS] = a5; yp[6 * UNITS] = a6; yp[7 * UNITS] = a7;
    }
}

extern "C" void kernel_launch(void* const* d_in, const int* in_sizes, int n_in,
                              void* d_out, int out_size, void* d_ws, size_t ws_size,
                              hipStream_t stream) {
    const float* x  = (const float*)d_in[0];   // [16384,1024]
    const float* W  = (const float*)d_in[1];   // [512,1024]
    const float* bv = (const float*)d_in[2];   // [512]
    const float* D  = (const float*)d_in[3];   // [512,1024]
    const float* GN = (const float*)d_in[4];   // [1,512,1024]
    float* y = (float*)d_out;                  // [16384,512]

    uint2* pkT = (uint2*)d_ws;                 // 32*512*8B = 128KB scratch

    topk_kernel<<<UNITS, 64, 0, stream>>>(D, GN, W, pkT);
    spmm_kernel<<<BATCH / BT, 512, 0, stream>>>(x, bv, pkT, y);
}

// Round 3
// 58.340 us; speedup vs baseline: 1.4657x; 1.0415x over previous
//
#include <hip/hip_runtime.h>
#include <stdint.h>

#define UNITS  512
#define IN_DIM 1024
#define KCONN  32
#define BATCH  16384
#define BT     16      // batches per tile
#define TILES  2       // tiles per block (double-buffered)

typedef float f32x2 __attribute__((ext_vector_type(2)));

// ---------------- Kernel 1: top-32 per unit ----------------
// pert[u,i] = D[u,i] + GN[0,u,i]; select the 32 largest (tie -> lower index,
// matching jax.lax.top_k). Only the index SET matters (summed one-hots).
// Output packed, k-major for coalesced streaming in spmm:
//   pkT[k*UNITS + u] = { px = i*32 + ((i&4)<<2)  (pre-swizzled LDS row addr),
//                        bits(W[u,i]) }

__device__ __forceinline__ uint32_t ordkey(float f) {
    uint32_t b = __float_as_uint(f);
    uint32_t mask = (b & 0x80000000u) ? 0xFFFFFFFFu : 0x80000000u;
    return b ^ mask;  // monotone: larger float -> larger uint
}

__global__ __launch_bounds__(64) void topk_kernel(const float* __restrict__ D,
                                                  const float* __restrict__ GN,
                                                  const float* __restrict__ W,
                                                  uint2* __restrict__ pkT) {
    const int u = blockIdx.x;
    const int l = threadIdx.x;

    unsigned long long keys[16];
#pragma unroll
    for (int j = 0; j < 16; ++j) {
        int i = l + 64 * j;                          // coalesced
        float v = D[u * IN_DIM + i] + GN[u * IN_DIM + i];
        keys[j] = ((unsigned long long)ordkey(v) << 32) |
                  (uint32_t)(0xFFFFFFFFu - (uint32_t)i);
    }
    unsigned long long best = keys[0];
#pragma unroll
    for (int j = 1; j < 16; ++j) best = keys[j] > best ? keys[j] : best;

    __shared__ int idxbuf[KCONN];

    for (int t = 0; t < KCONN; ++t) {
        unsigned long long g = best;
#pragma unroll
        for (int s = 1; s < 64; s <<= 1) {
            unsigned long long o = __shfl_xor(g, s, 64);
            g = o > g ? o : g;
        }
        if (best == g) {                // unique owner (keys unique via index bits)
            int i = (int)(0xFFFFFFFFu - (uint32_t)g);
            idxbuf[t] = i;
            int slot = i >> 6;
#pragma unroll
            for (int j = 0; j < 16; ++j)            // static indexing (no scratch)
                if (j == slot) keys[j] = 0;
            best = keys[0];
#pragma unroll
            for (int j = 1; j < 16; ++j) best = keys[j] > best ? keys[j] : best;
        }
    }
    __syncthreads();
    if (l < KCONN) {
        int i = idxbuf[l];
        float w = W[u * IN_DIM + i];
        uint32_t px = ((uint32_t)i << 5) | (((uint32_t)i & 4u) << 2);
        pkT[l * UNITS + u] = make_uint2(px, __float_as_uint(w));
    }
}

// ---------------- Kernel 2: sparse gather-GEMM ----------------
// y[b,u] = bias[u] + sum_k W[u,i] * x[b,i]
// LDS per tile: xs_T[i][b] bf16, 16 batches/row = 32B rows, 32 KB; two tiles
// double-buffered in 64 KB -> 2 blocks/CU. Chunk swizzle (16B granule):
//   phys = i*32 + (16h ^ ((i&4)<<2))  -- folded into pkT's px.
// Staging: two 4x4 quad shuffle-transposes -> 8 bf16/lane -> ds_write_b128.
// Tile 1 global loads issued into regs BEFORE tile-0 compute (T14 async-stage).
// Gather: lane = unit (u = w*64+l), 16 MACs/k via 2x ds_read_b128 + 8 v_pk_fma_f32.

__device__ __forceinline__ uint32_t f2bf_rne(float f) {
    uint32_t u = __float_as_uint(f);
    return (u + 0x7fffu + ((u >> 16) & 1u)) >> 16;   // round-to-nearest-even
}

__device__ __forceinline__ void mac2(f32x2& acc, uint32_t xw, f32x2 w2) {
    f32x2 xv;
    xv.x = __uint_as_float(xw << 16);          // low bf16 -> f32
    xv.y = __uint_as_float(xw & 0xffff0000u);  // high bf16 -> f32
    asm("v_pk_fma_f32 %0, %1, %2, %0" : "+v"(acc) : "v"(xv), "v"(w2));
}

// 4x4 transpose within a quad (verified in r2): input lane r holds row r's
// 4 cols {c..c+3}; output lane r holds col c+r's 4 rows.
#define QTRANS(f0, f1, f2, f3, o0, o1, o2, o3)                                   \
    {                                                                            \
        float t0 = r1 ? f1 : f0, t1 = r1 ? f2 : f1, t2 = r1 ? f3 : f2,           \
              t3 = r1 ? f0 : f3;                                                 \
        float g0 = r2m ? t2 : t0, g1 = r2m ? t3 : t1, g2 = r2m ? t0 : t2,        \
              g3 = r2m ? t1 : t3;                                                \
        float m0 = __shfl(g0, qb | (r & 3), 64);                                 \
        float m1 = __shfl(g1, qb | ((r - 1) & 3), 64);                           \
        float m2 = __shfl(g2, qb | ((r - 2) & 3), 64);                           \
        float m3 = __shfl(g3, qb | ((r - 3) & 3), 64);                           \
        float e0 = m0, e1 = m3, e2 = m2, e3 = m1;                                \
        float s0 = r1 ? e3 : e0, s1 = r1 ? e0 : e1, s2 = r1 ? e1 : e2,           \
              s3 = r1 ? e2 : e3;                                                 \
        o0 = r2m ? s2 : s0; o1 = r2m ? s3 : s1; o2 = r2m ? s0 : s2;              \
        o3 = r2m ? s1 : s3;                                                      \
    }

__device__ __forceinline__ void stage_write(char* dst, float4 vA, float4 vB,
                                            int r, int l, int c, int a) {
    const int r1 = r & 1, r2m = r & 2;
    const int qb = l & ~3;
    float o0, o1, o2, o3, p0, p1, p2, p3;
    QTRANS(vA.x, vA.y, vA.z, vA.w, o0, o1, o2, o3)   // rows 8a+0..3 of col c+r
    QTRANS(vB.x, vB.y, vB.z, vB.w, p0, p1, p2, p3)   // rows 8a+4..7 of col c+r
    const int i = c + r;
    uint32_t w0 = f2bf_rne(o0) | (f2bf_rne(o1) << 16);
    uint32_t w1 = f2bf_rne(o2) | (f2bf_rne(o3) << 16);
    uint32_t w2 = f2bf_rne(p0) | (f2bf_rne(p1) << 16);
    uint32_t w3 = f2bf_rne(p2) | (f2bf_rne(p3) << 16);
    uint32_t phys = (uint32_t)(i << 5) + (uint32_t)((a << 4) ^ ((i & 4) << 2));
    *(uint4*)(dst + phys) = make_uint4(w0, w1, w2, w3);
}

__device__ __forceinline__ void compute_tile(const char* xsb,
                                             const uint2* __restrict__ pkT,
                                             const float* __restrict__ bias,
                                             float* __restrict__ y,
                                             int u, int bb) {
    const float bv = bias[u];
    f32x2 acc[8];
#pragma unroll
    for (int m = 0; m < 8; ++m) { acc[m].x = bv; acc[m].y = bv; }

    const uint2* pkp = pkT + u;
#pragma unroll 8
    for (int k = 0; k < KCONN; ++k) {
        uint2 pk = pkp[(size_t)k << 9];            // coalesced 512B per wave
        uint4 xa = *(const uint4*)(xsb + pk.x);           // batches 0..7
        uint4 xb = *(const uint4*)(xsb + (pk.x ^ 16u));   // batches 8..15
        float wf = __uint_as_float(pk.y);
        f32x2 w2; w2.x = wf; w2.y = wf;
        mac2(acc[0], xa.x, w2); mac2(acc[1], xa.y, w2);
        mac2(acc[2], xa.z, w2); mac2(acc[3], xa.w, w2);
        mac2(acc[4], xb.x, w2); mac2(acc[5], xb.y, w2);
        mac2(acc[6], xb.z, w2); mac2(acc[7], xb.w, w2);
    }
    float* yp = y + (size_t)bb * UNITS + u;
#pragma unroll
    for (int m = 0; m < 8; ++m) {
        yp[(size_t)(2 * m) * UNITS]     = acc[m].x;
        yp[(size_t)(2 * m + 1) * UNITS] = acc[m].y;
    }
}

__global__ __launch_bounds__(512, 4) void spmm_kernel(const float* __restrict__ x,
                                                      const float* __restrict__ bias,
                                                      const uint2* __restrict__ pkT,
                                                      float* __restrict__ y) {
    __shared__ char xsb[TILES * 32768];             // 64 KB -> 2 blocks/CU

    const int tid = threadIdx.x;
    const int w = tid >> 6;                         // wave 0..7
    const int l = tid & 63;
    const int r = l & 3;                            // quad lane
    const int q16 = l >> 2;                         // quad id 0..15
    const int a = w & 1;                            // batch octet (rows 8a..8a+7)
    const int Q = w >> 1;                           // col quarter (256 cols)
    const int b0 = blockIdx.x * (BT * TILES);
    const int u = w * 64 + l;                       // one unit per lane

    const float* xrA = x + (size_t)(b0 + 8 * a + r) * IN_DIM;
    const float* xrB = xrA + 4 * IN_DIM;
    const int cbase = Q * 256 + q16 * 4;

    // ---- tile 0: load + transpose + write ----
#pragma unroll
    for (int j = 0; j < 4; ++j) {
        const int c = cbase + j * 64;
        float4 vA = *(const float4*)(xrA + c);
        float4 vB = *(const float4*)(xrB + c);
        stage_write(xsb, vA, vB, r, l, c, a);
    }

    // ---- issue tile-1 loads early (consumed after compute0; T14) ----
    float4 pA[4], pB[4];
#pragma unroll
    for (int j = 0; j < 4; ++j) {
        const int c = cbase + j * 64;
        pA[j] = *(const float4*)(xrA + BT * IN_DIM + c);
        pB[j] = *(const float4*)(xrB + BT * IN_DIM + c);
    }

    __syncthreads();
    compute_tile(xsb, pkT, bias, y, u, b0);

#pragma unroll
    for (int j = 0; j < 4; ++j)
        stage_write(xsb + 32768, pA[j], pB[j], r, l, cbase + j * 64, a);

    __syncthreads();
    compute_tile(xsb + 32768, pkT, bias, y, u, b0 + BT);
}

extern "C" void kernel_launch(void* const* d_in, const int* in_sizes, int n_in,
                              void* d_out, int out_size, void* d_ws, size_t ws_size,
                              hipStream_t stream) {
    const float* x  = (const float*)d_in[0];   // [16384,1024]
    const float* W  = (const float*)d_in[1];   // [512,1024]
    const float* bv = (const float*)d_in[2];   // [512]
    const float* D  = (const float*)d_in[3];   // [512,1024]
    const float* GN = (const float*)d_in[4];   // [1,512,1024]
    float* y = (float*)d_out;                  // [16384,512]

    uint2* pkT = (uint2*)d_ws;                 // 32*512*8B = 128KB scratch

    topk_kernel<<<UNITS, 64, 0, stream>>>(D, GN, W, pkT);
    spmm_kernel<<<BATCH / (BT * TILES), 512, 0, stream>>>(x, bv, pkT, y);
}

// Round 5
// 49.625 us; speedup vs baseline: 1.7232x; 1.1756x over previous
//
#include <hip/hip_runtime.h>
#include <stdint.h>

#define UNITS  512
#define IN_DIM 1024
#define KCONN  32
#define BATCH  16384
#define BT     16      // batches per block tile

// ---------------- Kernel 1: top-32 per unit (DPP, no DS ops) ----------------
// pert[u,i] = D[u,i] + GN[0,u,i]; select the 32 largest. Only the index SET
// matters downstream (one-hots are summed), so selection order / exact
// tie-break is irrelevant (values are continuous; exact ties ~never happen).
// Output packed k-major: pkT[k*UNITS+u] = { px = i*32 + ((i&4)<<2), bits(W[u,i]) }
// (px = pre-swizzled LDS row address matching spmm's staging layout.)

template <int CTRL, int RM>
__device__ __forceinline__ float dppmax(float m) {
    // lanes with no valid dpp source get -inf (old value), harmless for max
    int t = __builtin_amdgcn_update_dpp(0xFF800000, __float_as_int(m),
                                        CTRL, RM, 0xf, false);
    return fmaxf(m, __int_as_float(t));
}

__global__ __launch_bounds__(64) void topk_kernel(const float* __restrict__ D,
                                                  const float* __restrict__ GN,
                                                  const float* __restrict__ W,
                                                  uint2* __restrict__ pkT) {
    const int u = blockIdx.x;
    const int l = threadIdx.x;

    float cand[16];
#pragma unroll
    for (int j = 0; j < 16; ++j) {
        int i = l + 64 * j;                          // coalesced
        cand[j] = D[u * IN_DIM + i] + GN[u * IN_DIM + i];
    }

    int mykeep = -1;

    for (int t = 0; t < KCONN; ++t) {
        // local argmax over 16 register slots
        float bv = cand[0];
        int bs = 0;
#pragma unroll
        for (int j = 1; j < 16; ++j) {
            bool gt = cand[j] > bv;
            bv = gt ? cand[j] : bv;
            bs = gt ? j : bs;
        }
        // wave max via DPP (VALU pipe only): row_shr 1,2,4,8 + row_bcast15/31
        float m = bv;
        m = dppmax<0x111, 0xf>(m);
        m = dppmax<0x112, 0xf>(m);
        m = dppmax<0x114, 0xf>(m);
        m = dppmax<0x118, 0xf>(m);
        m = dppmax<0x142, 0xa>(m);   // row_bcast15 -> rows 1,3
        m = dppmax<0x143, 0xc>(m);   // row_bcast31 -> rows 2,3
        float gmax = __int_as_float(__builtin_amdgcn_readlane(__float_as_int(m), 63));

        unsigned long long mask = __ballot(bv == gmax);
        int owner = __ffsll((long long)mask) - 1;
        int slot = __builtin_amdgcn_readlane(bs, owner);
        int idx = slot * 64 + owner;                 // global column index

        if (l == t) mykeep = idx;
        // removal (uniform, unrolled -> no scratch)
        bool own = (l == owner);
#pragma unroll
        for (int j = 0; j < 16; ++j)
            cand[j] = (own && j == slot) ? -__builtin_huge_valf() : cand[j];
    }

    if (l < KCONN) {
        int i = mykeep;
        float w = W[u * IN_DIM + i];
        uint32_t px = ((uint32_t)i << 5) | (((uint32_t)i & 4u) << 2);
        pkT[l * UNITS + u] = make_uint2(px, __float_as_uint(w));
    }
}

// ---------------- Kernel 2: sparse gather-GEMM ----------------
// y[b,u] = bias[u] + sum_k W[u,i] * x[b,i]
// LDS: xs_T[i][b] f16, 16 batches/row = 32B rows, 32 KB. Chunk swizzle (16B):
//   chunk for batches 8a..8a+7 of row i lives at i*32 + 16*(a ^ ((i>>2)&1)).
//   pkT's px points at the a=0 chunk; px^16 is the a=1 chunk. (r2/r3-verified.)
// Each lane owns one unit (u = tid); its 32 pk entries are loaded into
// REGISTERS up front -> inner loop is pure LDS+VALU, fully pipelinable.
// MAC: v_fma_mix_f32 consumes packed f16 halves directly into f32 FMAs
// (1 VALU/MAC, no unpack; W exact f32; f16 x-rounding only, ~1e-3 abs err).

typedef float f32x2 __attribute__((ext_vector_type(2)));

__device__ __forceinline__ uint32_t pkh2(float a, float b) {
    union { _Float16 h; uint16_t u; } ua, ub;
    ua.h = (_Float16)a;
    ub.h = (_Float16)b;
    return (uint32_t)ua.u | ((uint32_t)ub.u << 16);
}

__device__ __forceinline__ void mix_lo(float& acc, uint32_t xh, float w) {
    asm("v_fma_mix_f32 %0, %1, %2, %0 op_sel_hi:[1,0,0]"
        : "+v"(acc) : "v"(xh), "v"(w));
}
__device__ __forceinline__ void mix_hi(float& acc, uint32_t xh, float w) {
    asm("v_fma_mix_f32 %0, %1, %2, %0 op_sel:[1,0,0] op_sel_hi:[1,0,0]"
        : "+v"(acc) : "v"(xh), "v"(w));
}

// 4x4 transpose within a quad (r2/r3-verified): input lane r holds row r's
// 4 cols {c..c+3}; output lane r holds col c+r's 4 rows.
#define QTRANS(f0, f1, f2, f3, o0, o1, o2, o3)                                   \
    {                                                                            \
        float t0 = r1 ? f1 : f0, t1 = r1 ? f2 : f1, t2 = r1 ? f3 : f2,           \
              t3 = r1 ? f0 : f3;                                                 \
        float g0 = r2m ? t2 : t0, g1 = r2m ? t3 : t1, g2 = r2m ? t0 : t2,        \
              g3 = r2m ? t1 : t3;                                                \
        float m0 = __shfl(g0, qb | (r & 3), 64);                                 \
        float m1 = __shfl(g1, qb | ((r - 1) & 3), 64);                           \
        float m2 = __shfl(g2, qb | ((r - 2) & 3), 64);                           \
        float m3 = __shfl(g3, qb | ((r - 3) & 3), 64);                           \
        float e0 = m0, e1 = m3, e2 = m2, e3 = m1;                                \
        float s0 = r1 ? e3 : e0, s1 = r1 ? e0 : e1, s2 = r1 ? e1 : e2,           \
              s3 = r1 ? e2 : e3;                                                 \
        o0 = r2m ? s2 : s0; o1 = r2m ? s3 : s1; o2 = r2m ? s0 : s2;              \
        o3 = r2m ? s1 : s3;                                                      \
    }

__global__ __launch_bounds__(512, 4) void spmm_kernel(const float* __restrict__ x,
                                                      const float* __restrict__ bias,
                                                      const uint2* __restrict__ pkT,
                                                      float* __restrict__ y) {
    __shared__ uint4 xs4[2048];                     // 32 KB
    char* xsb = (char*)xs4;

    const int tid = threadIdx.x;
    const int w = tid >> 6;                         // wave 0..7
    const int l = tid & 63;
    const int r = l & 3;                            // quad lane
    const int q16 = l >> 2;                         // quad id 0..15
    const int a = w & 1;                            // batch octet (rows 8a..8a+7)
    const int Q = w >> 1;                           // col quarter (256 cols)
    const int b0 = blockIdx.x * BT;
    const int u = tid;                              // one unit per lane

    // ---- load this lane's 32 pk entries into registers (issue first) ----
    uint2 pkreg[KCONN];
#pragma unroll
    for (int k = 0; k < KCONN; ++k) pkreg[k] = pkT[k * UNITS + u];
    const float bvv = bias[u];

    // ---- stage: x[b0..b0+15][:] f32 -> f16 xs_T[i][b], transposed ----
    const float* xrA = x + (size_t)(b0 + 8 * a + r) * IN_DIM;
    const float* xrB = xrA + 4 * IN_DIM;
    const int r1 = r & 1, r2m = r & 2;
    const int qb = l & ~3;
#pragma unroll
    for (int j = 0; j < 4; ++j) {
        const int c = Q * 256 + q16 * 4 + j * 64;
        float4 vA = *(const float4*)(xrA + c);
        float4 vB = *(const float4*)(xrB + c);
        float o0, o1, o2, o3, p0, p1, p2, p3;
        QTRANS(vA.x, vA.y, vA.z, vA.w, o0, o1, o2, o3)   // rows 8a+0..3 of col c+r
        QTRANS(vB.x, vB.y, vB.z, vB.w, p0, p1, p2, p3)   // rows 8a+4..7 of col c+r
        const int i = c + r;
        uint4 pkd = make_uint4(pkh2(o0, o1), pkh2(o2, o3),
                               pkh2(p0, p1), pkh2(p2, p3));
        uint32_t phys = (uint32_t)(i << 5) + (uint32_t)((a << 4) ^ ((i & 4) << 2));
        *(uint4*)(xsb + phys) = pkd;
    }
    __syncthreads();

    // ---- gather: 32 k x { 2x ds_read_b128 + 16x v_fma_mix_f32 } ----
    float acc[BT];
#pragma unroll
    for (int b = 0; b < BT; ++b) acc[b] = bvv;

#pragma unroll
    for (int k = 0; k < KCONN; ++k) {
        uint2 pk = pkreg[k];
        uint4 xa = *(const uint4*)(xsb + pk.x);           // batches 0..7
        uint4 xb = *(const uint4*)(xsb + (pk.x ^ 16u));   // batches 8..15
        float wv = __uint_as_float(pk.y);
        mix_lo(acc[0], xa.x, wv);  mix_hi(acc[1], xa.x, wv);
        mix_lo(acc[2], xa.y, wv);  mix_hi(acc[3], xa.y, wv);
        mix_lo(acc[4], xa.z, wv);  mix_hi(acc[5], xa.z, wv);
        mix_lo(acc[6], xa.w, wv);  mix_hi(acc[7], xa.w, wv);
        mix_lo(acc[8], xb.x, wv);  mix_hi(acc[9], xb.x, wv);
        mix_lo(acc[10], xb.y, wv); mix_hi(acc[11], xb.y, wv);
        mix_lo(acc[12], xb.z, wv); mix_hi(acc[13], xb.z, wv);
        mix_lo(acc[14], xb.w, wv); mix_hi(acc[15], xb.w, wv);
    }

    float* yp = y + (size_t)b0 * UNITS + u;
#pragma unroll
    for (int b = 0; b < BT; ++b) yp[(size_t)b * UNITS] = acc[b];
}

extern "C" void kernel_launch(void* const* d_in, const int* in_sizes, int n_in,
                              void* d_out, int out_size, void* d_ws, size_t ws_size,
                              hipStream_t stream) {
    const float* x  = (const float*)d_in[0];   // [16384,1024]
    const float* W  = (const float*)d_in[1];   // [512,1024]
    const float* bv = (const float*)d_in[2];   // [512]
    const float* D  = (const float*)d_in[3];   // [512,1024]
    const float* GN = (const float*)d_in[4];   // [1,512,1024]
    float* y = (float*)d_out;                  // [16384,512]

    uint2* pkT = (uint2*)d_ws;                 // 32*512*8B = 128KB scratch

    topk_kernel<<<UNITS, 64, 0, stream>>>(D, GN, W, pkT);
    spmm_kernel<<<BATCH / BT, 512, 0, stream>>>(x, bv, pkT, y);
}